// Round 17
// baseline (2796.580 us; speedup 1.0000x reference)
//
#include <hip/hip_runtime.h>
#include <hip/hip_bf16.h>
#include <math.h>

#define Bn 16
#define Tn 512
#define Dn 1024
#define Hn 8
#define Ln 6
#define Fn 4096
#define HDn 128

typedef __attribute__((ext_vector_type(8))) short short8;
typedef __attribute__((ext_vector_type(4))) short short4v;
typedef __attribute__((ext_vector_type(4))) float f32x4;

__device__ __forceinline__ float bf2f(unsigned short u){
  union{float f; unsigned int i;} c; c.i = ((unsigned int)u)<<16; return c.f;
}
__device__ __forceinline__ unsigned short f2bf(float f){
  union{float f; unsigned int i;} c; c.f=f;
  unsigned int r = c.i + 0x7fffu + ((c.i>>16)&1u);
  return (unsigned short)(r>>16);
}
// pref(h): pooled-token prefix offset (rows of S) for head h; S_h = 512>>(h>>1)
__device__ __forceinline__ int pref_of(int h){
  int g = h >> 1;
  return (2048 - (2048 >> g)) + (h & 1) * (512 >> g);
}
__device__ __forceinline__ int kvoff_of(int g){   // row offset of group g in kvbuf
  return (g==0)?0:(g==1)?8192:(g==2)?12288:14336;
}

#define GLOAD(gp, lp) __builtin_amdgcn_global_load_lds( \
    (const __attribute__((address_space(1))) void*)(const void*)(gp), \
    (__attribute__((address_space(3))) void*)(void*)(lp), 16, 0, 0)

// ---------------- embedding: x[b,t,:] = embed[tok] + pos[t] ----------------
__global__ __launch_bounds__(256) void embed_kernel(
    const int* __restrict__ tok, const float* __restrict__ emb,
    const float* __restrict__ pos, float* __restrict__ x){
  long row = blockIdx.x;                 // b*T + t
  int t = (int)(row & (Tn-1));
  int tk = tok[row];
  int d = threadIdx.x*4;
  float4 e = *(const float4*)(emb + (long)tk*Dn + d);
  float4 p = *(const float4*)(pos + (long)t*Dn + d);
  float4 r; r.x=e.x+p.x; r.y=e.y+p.y; r.z=e.z+p.z; r.w=e.w+p.w;
  *(float4*)(x + row*(long)Dn + d) = r;
}

// ---------------- LayerNorm over D=1024 (one block per row) ----------------
template<int OUTBF>
__global__ __launch_bounds__(256) void ln_kernel(
    const float* __restrict__ x, const float* __restrict__ g,
    const float* __restrict__ b, void* __restrict__ outp){
  long row = blockIdx.x;
  const float* xr = x + row*(long)Dn;
  int tid = threadIdx.x;
  float4 v4 = *(const float4*)(xr + tid*4);
  float s  = v4.x+v4.y+v4.z+v4.w;
  float s2 = v4.x*v4.x + v4.y*v4.y + v4.z*v4.z + v4.w*v4.w;
  #pragma unroll
  for (int o=32;o;o>>=1){ s += __shfl_xor(s,o); s2 += __shfl_xor(s2,o); }
  __shared__ float rs[4], rs2[4];
  int w = tid>>6;
  if ((tid&63)==0){ rs[w]=s; rs2[w]=s2; }
  __syncthreads();
  s  = rs[0]+rs[1]+rs[2]+rs[3];
  s2 = rs2[0]+rs2[1]+rs2[2]+rs2[3];
  float mu  = s*(1.f/Dn);
  float var = s2*(1.f/Dn) - mu*mu;
  float rstd = rsqrtf(var + 1e-5f);
  float4 gg = *(const float4*)(g + tid*4);
  float4 bb = *(const float4*)(b + tid*4);
  float o0 = (v4.x-mu)*rstd*gg.x + bb.x;
  float o1 = (v4.y-mu)*rstd*gg.y + bb.y;
  float o2 = (v4.z-mu)*rstd*gg.z + bb.z;
  float o3 = (v4.w-mu)*rstd*gg.w + bb.w;
  if (OUTBF){
    unsigned short* o = (unsigned short*)outp + row*(long)Dn + tid*4;
    o[0]=f2bf(o0); o[1]=f2bf(o1); o[2]=f2bf(o2); o[3]=f2bf(o3);
  } else {
    float* o = (float*)outp + row*(long)Dn + tid*4;
    o[0]=o0; o[1]=o1; o[2]=o2; o[3]=o3;
  }
}

// ------------- weight transpose+convert: W[K][N] f32 -> WT[N][K] bf16 -------
__global__ __launch_bounds__(256) void transpose_w(
    const float* __restrict__ W, unsigned short* __restrict__ WT, int Kd, int Nd){
  __shared__ float tile[32][33];
  long lofs = (long)blockIdx.z * Kd * Nd;
  int n0 = blockIdx.x*32, k0 = blockIdx.y*32;
  int tx = threadIdx.x & 31, ty = threadIdx.x >> 5;   // ty 0..7
  #pragma unroll
  for (int i=0;i<4;i++){
    int kk = k0 + ty + i*8;
    tile[ty+i*8][tx] = W[lofs + (long)kk*Nd + n0 + tx];
  }
  __syncthreads();
  #pragma unroll
  for (int i=0;i<4;i++){
    int nn = n0 + ty + i*8;
    WT[lofs + (long)nn*Kd + k0 + tx] = f2bf(tile[tx][ty+i*8]);
  }
}

// ---- pack grouped K/V weights: wkvT[l][g][512][1024] from WkT, WvT --------
__global__ __launch_bounds__(256) void pack_wkv(
    const unsigned short* __restrict__ WkT, const unsigned short* __restrict__ WvT,
    unsigned short* __restrict__ wkvT){
  int i8 = blockIdx.x*256 + threadIdx.x;    // short8 chunk index
  int c8 = i8 & 127;
  int r  = (i8 >> 7) & 511;
  int g  = (i8 >> 16) & 3;
  int l  = i8 >> 18;
  const unsigned short* src = (r < 256)
      ? WkT + ((long)l<<20) + (long)(g*256 + r)*1024 + c8*8
      : WvT + ((long)l<<20) + (long)(g*256 + (r-256))*1024 + c8*8;
  *(short8*)(wkvT + (long)i8*8) = *(const short8*)src;
}

// ---- pack grouped K/V biases: bkv[l][g][512] --------------------------------
__global__ __launch_bounds__(256) void pack_bkv(
    const float* __restrict__ bk, const float* __restrict__ bv,
    float* __restrict__ bkv){
  int i = blockIdx.x*256 + threadIdx.x;     // < Ln*4*512
  int c = i & 511;
  int g = (i >> 9) & 3;
  int l = i >> 11;
  bkv[i] = (c < 256) ? bk[l*1024 + g*256 + c] : bv[l*1024 + g*256 + (c-256)];
}

// ------- circulant kernel c = irfft(gate per rfft-bin), per (layer,head) ----
__global__ __launch_bounds__(512) void ckern(
    const float* __restrict__ gates, float* __restrict__ cbuf){
  int lh = blockIdx.x;                   // l*H + h
  __shared__ float gb[16];
  if (threadIdx.x < 16) gb[threadIdx.x] = gates[lh*16 + threadIdx.x];
  __syncthreads();
  int m = threadIdx.x;                   // 0..511
  float acc = gb[0];                     // bin 0, weight 1, band 0
  for (int j=1;j<256;j++){
    int band = (j*16)/257;               // (j*BANDS)//nb
    int kmod = (j*m) & 511;              // exact phase reduction
    acc += 2.f*gb[band]*cosf(1.2271846303085129e-2f * (float)kmod); // 2pi/512
  }
  acc += gb[15] * ((m & 1) ? -1.f : 1.f);   // Nyquist bin, band 15
  cbuf[lh*512 + m] = acc * (1.f/512.f);
}

// --------- materialize G[l,h,t,s] = c[(t-s) mod 512] as bf16 ---------------
__global__ __launch_bounds__(256) void gfill(
    const float* __restrict__ cbuf, unsigned short* __restrict__ G){
  long idx = (long)blockIdx.x*256 + threadIdx.x;   // grid sized exactly
  int lh = (int)(idx >> 18);
  int rem = (int)(idx & 262143);
  int t = rem >> 9, s = rem & 511;
  G[idx] = f2bf(cbuf[lh*512 + ((t - s) & 511)]);
}

// ---- pool hbuf rows for groups g=1..3: P rows {4096,2048,1024} x 1024 -------
__global__ __launch_bounds__(256) void pool_x(
    const unsigned short* __restrict__ hbuf, unsigned short* __restrict__ P){
  int rid = blockIdx.x;                     // < 7168
  int g, S, idx;
  if (rid < 4096){ g=1; S=256; idx=rid; }
  else if (rid < 6144){ g=2; S=128; idx=rid-4096; }
  else { g=3; S=64; idx=rid-6144; }
  int r = 1 << g;
  int b = idx / S, s = idx - b*S;
  const unsigned short* src = hbuf + ((long)(b*512 + s*r))*1024 + threadIdx.x*4;
  float a0=0.f, a1=0.f, a2=0.f, a3=0.f;
  for (int j=0;j<r;j++){
    short4v v = *(const short4v*)(src + (long)j*1024);
    a0 += bf2f((unsigned short)v[0]); a1 += bf2f((unsigned short)v[1]);
    a2 += bf2f((unsigned short)v[2]); a3 += bf2f((unsigned short)v[3]);
  }
  float inv = 1.f/(float)r;
  unsigned short* dst = P + (long)rid*1024 + threadIdx.x*4;
  dst[0]=f2bf(a0*inv); dst[1]=f2bf(a1*inv); dst[2]=f2bf(a2*inv); dst[3]=f2bf(a3*inv);
}

// ---- transpose pooled V out of kvbuf into vTp[head-packed][b][d][s] ---------
__global__ __launch_bounds__(256) void vtrans(
    const unsigned short* __restrict__ kvbuf, unsigned short* __restrict__ vTp){
  __shared__ unsigned short tile[32][33];
  int z = blockIdx.z;                 // h*16 + b
  int h = z >> 4, b = z & 15;
  int g = h >> 1, dlt = h & 1;
  int S = 512 >> g;
  int s0 = blockIdx.x*32;
  if (s0 >= S) return;
  int d0 = blockIdx.y*32;
  int kvbase = kvoff_of(g) + b*S;
  int colbase = 256 + dlt*128 + d0;
  int tx = threadIdx.x & 31, ty = threadIdx.x >> 5;   // ty 0..7
  #pragma unroll
  for (int i=0;i<4;i++){
    int s = s0 + ty + i*8;
    tile[ty+i*8][tx] = kvbuf[(long)(kvbase + s)*512 + colbase + tx];
  }
  __syncthreads();
  long basep = (long)Bn*HDn*pref_of(h);
  #pragma unroll
  for (int i=0;i<4;i++){
    int d = d0 + ty + i*8;
    vTp[basep + ((long)(b*128 + d))*S + s0 + tx] = tile[tx][ty+i*8];
  }
}

// --------- merged row softmax over ALL heads (variable S per head) ----------
// 512 threads = 8 waves, one row per wave.
__global__ __launch_bounds__(512) void softmax_all(
    const float* __restrict__ sc, unsigned short* __restrict__ at){
  long rid = (long)blockIdx.x*8 + (threadIdx.x >> 6);
  int head = (int)(rid >> 13);
  int rih  = (int)(rid & 8191);
  int g = head >> 1;
  int S = 512 >> g;
  int NV = S >> 6;
  long base = (long)Bn*Tn*pref_of(head) + (long)rih*S;
  const float* r = sc + base;
  int lane = threadIdx.x & 63;
  float vals[8];
  float mx = -1e30f;
  #pragma unroll
  for (int i=0;i<8;i++){
    if (i < NV){ vals[i] = r[lane + i*64] * 0.08838834764831845f; mx = fmaxf(mx, vals[i]); }
  }
  #pragma unroll
  for (int o=32;o;o>>=1) mx = fmaxf(mx, __shfl_xor(mx, o));
  float sum = 0.f;
  #pragma unroll
  for (int i=0;i<8;i++){
    if (i < NV){ vals[i] = expf(vals[i]-mx); sum += vals[i]; }
  }
  #pragma unroll
  for (int o=32;o;o>>=1) sum += __shfl_xor(sum, o);
  float inv = 1.f/sum;
  unsigned short* ab = at + base;
  #pragma unroll
  for (int i=0;i<8;i++){
    if (i < NV) ab[lane + i*64] = f2bf(vals[i]*inv);
  }
}

// ----------------- generic batched bf16 MFMA GEMM (gating path) -------------
// r7-proven schedule: stage(t+1); vmcnt(8); barrier; compute; barrier.
template<int MODE>
__global__ __launch_bounds__(256)
void gemm_kernel(const unsigned short* __restrict__ A, int lda, long sAb, long sAh,
                 const unsigned short* __restrict__ Bt, int ldb, long sBb, long sBh,
                 void* __restrict__ Cout, int ldc, long sCb, long sCh,
                 const float* __restrict__ bias, long sbias,
                 int zshift, int zmask,
                 int M, int N, int K)
{
  __shared__ unsigned short AB[2][2][128*64];
  int z = blockIdx.z;
  int zb = z & zmask, zh = z >> zshift;
  const unsigned short* Az = A + (long)zb*sAb + (long)zh*sAh;
  const unsigned short* Bz = Bt + (long)zb*sBb + (long)zh*sBh;
  const float* biasz = bias ? (bias + (long)zh*sbias) : nullptr;
  int m0 = blockIdx.y*128, n0 = blockIdx.x*128;
  int tid = threadIdx.x;
  int lane = tid & 63, wid = tid >> 6;
  int wm = wid >> 1, wn = wid & 1;
  f32x4 zero4 = {0.f,0.f,0.f,0.f};
  f32x4 acc[4][4];
  #pragma unroll
  for (int m=0;m<4;m++)
    #pragma unroll
    for (int n=0;n<4;n++)
      acc[m][n] = zero4;
  const int r16 = lane & 15, kq = lane >> 4;

  auto stage = [&](int buf, int k0){
    #pragma unroll
    for (int i=0;i<4;i++){
      int chunk = i*256 + tid;
      int row = chunk >> 3, c = chunk & 7;
      int cg = (c ^ (row & 7)) * 8;
      int gm = m0 + row; gm = gm < M ? gm : M-1;
      GLOAD(Az + (long)gm*lda + k0 + cg, AB[buf][0] + (i*256 + wid*64)*8);
    }
    #pragma unroll
    for (int i=0;i<4;i++){
      int chunk = i*256 + tid;
      int row = chunk >> 3, c = chunk & 7;
      int cg = (c ^ (row & 7)) * 8;
      int gn = n0 + row; gn = gn < N ? gn : N-1;
      GLOAD(Bz + (long)gn*ldb + k0 + cg, AB[buf][1] + (i*256 + wid*64)*8);
    }
  };

  int NT = K >> 6;
  stage(0, 0);
  for (int t = 0; t < NT; t++){
    if (t + 1 < NT){
      stage((t+1)&1, (t+1)*64);
      asm volatile("s_waitcnt vmcnt(8)" ::: "memory");
    } else {
      asm volatile("s_waitcnt vmcnt(0)" ::: "memory");
    }
    __builtin_amdgcn_s_barrier();
    const unsigned short* As = AB[t&1][0];
    const unsigned short* Bs = AB[t&1][1];
    #pragma unroll
    for (int kk=0; kk<64; kk+=32){
      short8 af[4], bfr[4];
      int kb = (kk + kq*8) * 2;
      #pragma unroll
      for (int m=0;m<4;m++){
        int row = wm*64 + m*16 + r16;
        af[m] = *(const short8*)((const char*)As + row*128 + (kb ^ ((row & 7) << 4)));
      }
      #pragma unroll
      for (int n=0;n<4;n++){
        int row = wn*64 + n*16 + r16;
        bfr[n] = *(const short8*)((const char*)Bs + row*128 + (kb ^ ((row & 7) << 4)));
      }
      #pragma unroll
      for (int m=0;m<4;m++)
        #pragma unroll
        for (int n=0;n<4;n++)
          acc[m][n] = __builtin_amdgcn_mfma_f32_16x16x32_bf16(af[m], bfr[n], acc[m][n], 0, 0, 0);
    }
    __builtin_amdgcn_s_barrier();
  }
  #pragma unroll
  for (int n=0;n<4;n++){
    int col = n0 + wn*64 + n*16 + r16;
    if (col >= N) continue;
    float bvv = 0.f;
    if (MODE != 0 && biasz != nullptr) bvv = biasz[col];
    #pragma unroll
    for (int m=0;m<4;m++){
      #pragma unroll
      for (int e=0;e<4;e++){
        int row = m0 + wm*64 + m*16 + kq*4 + e;
        if (row >= M) continue;
        float vv = acc[m][n][e] + bvv;
        long cidx = (long)zb*sCb + (long)zh*sCh + (long)row*ldc + col;
        if (MODE == 0)      ((float*)Cout)[cidx] = vv;
        else                ((unsigned short*)Cout)[cidx] = f2bf(vv);
      }
    }
  }
}

// -------- merged scores GEMM, all heads: reads k-half of kvbuf (ldb=512) ----
__global__ __launch_bounds__(256)
void scores_all(const unsigned short* __restrict__ q,
                const unsigned short* __restrict__ kvbuf,
                float* __restrict__ sc)
{
  __shared__ unsigned short AB[2][2][128*64];
  int z = blockIdx.z;
  int zb = z & 15, zh = z >> 4;
  int g = zh >> 1, dlt = zh & 1;
  int S = 512 >> g;
  int n0 = blockIdx.x*128;
  if (n0 >= S) return;
  int pf = pref_of(zh);
  const unsigned short* Az = q + (long)zb*Tn*Dn + (long)zh*HDn;
  const unsigned short* Bz = kvbuf + (long)(kvoff_of(g) + zb*S)*512 + dlt*128;
  float* Cz = sc + (long)Bn*Tn*pf + (long)zb*Tn*S;
  int m0 = blockIdx.y*128;
  int tid = threadIdx.x;
  int lane = tid & 63, wid = tid >> 6;
  int wm = wid >> 1, wn = wid & 1;
  f32x4 zero4 = {0.f,0.f,0.f,0.f};
  f32x4 acc[4][4];
  #pragma unroll
  for (int m=0;m<4;m++)
    #pragma unroll
    for (int n=0;n<4;n++)
      acc[m][n] = zero4;
  const int r16 = lane & 15, kq = lane >> 4;

  auto stage = [&](int buf, int k0){
    #pragma unroll
    for (int i=0;i<4;i++){
      int chunk = i*256 + tid;
      int row = chunk >> 3, c = chunk & 7;
      int cg = (c ^ (row & 7)) * 8;
      GLOAD(Az + (long)(m0 + row)*Dn + k0 + cg, AB[buf][0] + (i*256 + wid*64)*8);
    }
    #pragma unroll
    for (int i=0;i<4;i++){
      int chunk = i*256 + tid;
      int row = chunk >> 3, c = chunk & 7;
      int cg = (c ^ (row & 7)) * 8;
      int gn = n0 + row; gn = gn < S ? gn : S-1;
      GLOAD(Bz + (long)gn*512 + k0 + cg, AB[buf][1] + (i*256 + wid*64)*8);
    }
  };

  stage(0, 0);
  stage(1, 64);                             // K = HDn = 128 -> exactly 2 tiles
  #pragma unroll
  for (int t = 0; t < 2; t++){
    if (t == 0) { asm volatile("s_waitcnt vmcnt(8)" ::: "memory"); }
    else        { asm volatile("s_waitcnt vmcnt(0)" ::: "memory"); }
    __builtin_amdgcn_s_barrier();
    const unsigned short* As = AB[t][0];
    const unsigned short* Bs = AB[t][1];
    #pragma unroll
    for (int kk=0; kk<64; kk+=32){
      short8 af[4], bfr[4];
      int kb = (kk + kq*8) * 2;
      #pragma unroll
      for (int m=0;m<4;m++){
        int row = wm*64 + m*16 + r16;
        af[m] = *(const short8*)((const char*)As + row*128 + (kb ^ ((row & 7) << 4)));
      }
      #pragma unroll
      for (int n=0;n<4;n++){
        int row = wn*64 + n*16 + r16;
        bfr[n] = *(const short8*)((const char*)Bs + row*128 + (kb ^ ((row & 7) << 4)));
      }
      #pragma unroll
      for (int m=0;m<4;m++)
        #pragma unroll
        for (int n=0;n<4;n++)
          acc[m][n] = __builtin_amdgcn_mfma_f32_16x16x32_bf16(af[m], bfr[n], acc[m][n], 0, 0, 0);
    }
    __builtin_amdgcn_s_barrier();
  }
  #pragma unroll
  for (int n=0;n<4;n++){
    int col = n0 + wn*64 + n*16 + r16;
    if (col >= S) continue;
    #pragma unroll
    for (int m=0;m<4;m++){
      #pragma unroll
      for (int e=0;e<4;e++){
        int row = m0 + wm*64 + m*16 + kq*4 + e;
        Cz[(long)row*S + col] = acc[m][n][e];
      }
    }
  }
}

// -------- merged PV GEMM, all heads: oT[zh][zb][d][t], runtime K=S(zh) ------
__global__ __launch_bounds__(256)
void pv_all(const unsigned short* __restrict__ vTp,
            const unsigned short* __restrict__ at,
            unsigned short* __restrict__ oT)
{
  __shared__ unsigned short AB[2][2][128*64];
  int z = blockIdx.z;
  int zb = z & 15, zh = z >> 4;
  int g = zh >> 1;
  int S = 512 >> g;
  int pf = pref_of(zh);
  const unsigned short* Az = vTp + (long)Bn*HDn*pf + (long)zb*HDn*S;
  const unsigned short* Bz = at  + (long)Bn*Tn*pf  + (long)zb*Tn*S;
  unsigned short* Cz = oT + (long)zh*Bn*HDn*Tn + (long)zb*HDn*Tn;
  int n0 = blockIdx.x*128;
  int tid = threadIdx.x;
  int lane = tid & 63, wid = tid >> 6;
  int wm = wid >> 1, wn = wid & 1;
  f32x4 zero4 = {0.f,0.f,0.f,0.f};
  f32x4 acc[4][4];
  #pragma unroll
  for (int m=0;m<4;m++)
    #pragma unroll
    for (int n=0;n<4;n++)
      acc[m][n] = zero4;
  const int r16 = lane & 15, kq = lane >> 4;

  auto stage = [&](int buf, int k0){
    #pragma unroll
    for (int i=0;i<4;i++){
      int chunk = i*256 + tid;
      int row = chunk >> 3, c = chunk & 7;
      int cg = (c ^ (row & 7)) * 8;
      GLOAD(Az + (long)row*S + k0 + cg, AB[buf][0] + (i*256 + wid*64)*8);
    }
    #pragma unroll
    for (int i=0;i<4;i++){
      int chunk = i*256 + tid;
      int row = chunk >> 3, c = chunk & 7;
      int cg = (c ^ (row & 7)) * 8;
      GLOAD(Bz + (long)(n0 + row)*S + k0 + cg, AB[buf][1] + (i*256 + wid*64)*8);
    }
  };

  int NT = S >> 6;
  stage(0, 0);
  for (int t = 0; t < NT; t++){
    if (t + 1 < NT){
      stage((t+1)&1, (t+1)*64);
      asm volatile("s_waitcnt vmcnt(8)" ::: "memory");
    } else {
      asm volatile("s_waitcnt vmcnt(0)" ::: "memory");
    }
    __builtin_amdgcn_s_barrier();
    const unsigned short* As = AB[t&1][0];
    const unsigned short* Bs = AB[t&1][1];
    #pragma unroll
    for (int kk=0; kk<64; kk+=32){
      short8 af[4], bfr[4];
      int kb = (kk + kq*8) * 2;
      #pragma unroll
      for (int m=0;m<4;m++){
        int row = wm*64 + m*16 + r16;
        af[m] = *(const short8*)((const char*)As + row*128 + (kb ^ ((row & 7) << 4)));
      }
      #pragma unroll
      for (int n=0;n<4;n++){
        int row = wn*64 + n*16 + r16;
        bfr[n] = *(const short8*)((const char*)Bs + row*128 + (kb ^ ((row & 7) << 4)));
      }
      #pragma unroll
      for (int m=0;m<4;m++)
        #pragma unroll
        for (int n=0;n<4;n++)
          acc[m][n] = __builtin_amdgcn_mfma_f32_16x16x32_bf16(af[m], bfr[n], acc[m][n], 0, 0, 0);
    }
    __builtin_amdgcn_s_barrier();
  }
  #pragma unroll
  for (int n=0;n<4;n++){
    int col = n0 + wn*64 + n*16 + r16;
    #pragma unroll
    for (int m=0;m<4;m++){
      #pragma unroll
      for (int e=0;e<4;e++){
        int row = wm*64 + m*16 + kq*4 + e;
        Cz[(long)row*Tn + col] = f2bf(acc[m][n][e]);
      }
    }
  }
}

// ---- merged Q + grouped-K/V projection (z: 0,1 = Q halves; 2..5 = groups) --
// r7 2-barrier schedule; all sub-problems N=512 wide, K=1024.
__global__ __launch_bounds__(256)
void gemm_qkv(const unsigned short* __restrict__ hbuf,
              const unsigned short* __restrict__ P,
              const unsigned short* __restrict__ WqT_l,
              const unsigned short* __restrict__ wkvT_l,
              unsigned short* __restrict__ q,
              unsigned short* __restrict__ kvbuf,
              const float* __restrict__ bq_l,
              const float* __restrict__ bkv_l)
{
  __shared__ char shraw[2][32768];
  int z = blockIdx.z;
  int isQ = (z < 2);
  int g = isQ ? 0 : (z - 2);
  int Mg = isQ ? 8192 : (8192 >> g);
  int m0 = blockIdx.y*128;
  if (m0 >= Mg) return;                     // uniform exit, before any barrier
  int n0 = blockIdx.x*128;
  const unsigned short* Az = (isQ || g==0) ? hbuf
      : P + (long)((g==1)?0:(g==2)?4096:6144)*1024;
  const unsigned short* Bz = isQ ? (WqT_l + (long)z*512*1024)
                                 : (wkvT_l + (long)g*512*1024);
  const float* biasz = isQ ? (bq_l + z*512) : (bkv_l + g*512);
  unsigned short* Cz; int ldc;
  if (isQ){ Cz = q + z*512; ldc = 1024; }
  else    { Cz = kvbuf + (long)kvoff_of(g)*512; ldc = 512; }
  int tid = threadIdx.x;
  int lane = tid & 63, wid = tid >> 6;
  int wm = wid >> 1, wn = wid & 1;
  f32x4 zero4 = {0.f,0.f,0.f,0.f};
  f32x4 acc[4][4];
  #pragma unroll
  for (int m=0;m<4;m++)
    #pragma unroll
    for (int n=0;n<4;n++)
      acc[m][n] = zero4;
  const int r16 = lane & 15, kq = lane >> 4;

  auto stage = [&](int buf, int k0){
    unsigned short* As = (unsigned short*)shraw[buf];
    #pragma unroll
    for (int i=0;i<4;i++){
      int chunk = i*256 + tid;
      int row = chunk >> 3, c = chunk & 7;
      int cg = (c ^ (row & 7)) * 8;
      GLOAD(Az + (long)(m0 + row)*1024 + k0 + cg, As + (i*256 + wid*64)*8);
    }
    #pragma unroll
    for (int i=0;i<4;i++){
      int chunk = i*256 + tid;
      int row = chunk >> 3, c = chunk & 7;
      int cg = (c ^ (row & 7)) * 8;
      GLOAD(Bz + (long)(n0 + row)*1024 + k0 + cg, As + 8192 + (i*256 + wid*64)*8);
    }
  };

  const int NT = 16;                        // K = 1024
  stage(0, 0);
  for (int t = 0; t < NT; t++){
    if (t + 1 < NT){
      stage((t+1)&1, (t+1)*64);
      asm volatile("s_waitcnt vmcnt(8)" ::: "memory");
    } else {
      asm volatile("s_waitcnt vmcnt(0)" ::: "memory");
    }
    __builtin_amdgcn_s_barrier();
    const unsigned short* As = (const unsigned short*)shraw[t&1];
    const unsigned short* Bs = As + 8192;
    #pragma unroll
    for (int kk=0; kk<64; kk+=32){
      short8 af[4], bfr[4];
      int kb = (kk + kq*8) * 2;
      #pragma unroll
      for (int m=0;m<4;m++){
        int row = wm*64 + m*16 + r16;
        af[m] = *(const short8*)((const char*)As + row*128 + (kb ^ ((row & 7) << 4)));
      }
      #pragma unroll
      for (int n=0;n<4;n++){
        int row = wn*64 + n*16 + r16;
        bfr[n] = *(const short8*)((const char*)Bs + row*128 + (kb ^ ((row & 7) << 4)));
      }
      #pragma unroll
      for (int m=0;m<4;m++)
        #pragma unroll
        for (int n=0;n<4;n++)
          acc[m][n] = __builtin_amdgcn_mfma_f32_16x16x32_bf16(af[m], bfr[n], acc[m][n], 0, 0, 0);
    }
    __builtin_amdgcn_s_barrier();
  }

  unsigned short* shb = (unsigned short*)&shraw[0][0];
  #pragma unroll
  for (int n=0;n<4;n++){
    int col = wn*64 + n*16 + r16;
    float bvv = biasz[n0 + col];
    #pragma unroll
    for (int m=0;m<4;m++){
      #pragma unroll
      for (int e=0;e<4;e++){
        int row = wm*64 + m*16 + kq*4 + e;
        shb[row*136 + col] = f2bf(acc[m][n][e] + bvv);
      }
    }
  }
  __syncthreads();
  #pragma unroll
  for (int i=0;i<8;i++){
    int chunk = i*256 + tid;
    int row = chunk >> 4, col = (chunk & 15)*8;
    short8 vv8 = *(const short8*)(shb + row*136 + col);
    *(short8*)(Cz + (long)(m0 + row)*ldc + n0 + col) = vv8;
  }
}

// ----------------- static-shape 128x64-tile GEMM (Wo / FFN1 / FFN2) ---------
// OCCUPANCY VARIANT: LDS 48KB (A 16KB + B 8KB, double-buffered) -> 3 blocks/CU
// (vs 2 at 64KB) to overlap the vmcnt(0) drain across 3 barrier domains.
// r9 single-barrier schedule (+setprio). 4 waves, per-wave C = 64x32 (acc[4][2]).
// MODE 1: +bias -> bf16 | 2: +bias,GELU -> bf16 | 3: +bias, += into fp32 C
template<int MODE, int Mt, int Nt, int Kt, long SBH, long SCH, int BIASST>
__global__ __launch_bounds__(256)
void gemm_big(const unsigned short* __restrict__ A,
              const unsigned short* __restrict__ Bt,
              void* __restrict__ Cout,
              const float* __restrict__ bias)
{
  __shared__ char shraw[2][24576];   // per buf: A 16384B @0, B 8192B @16384
  int zh = blockIdx.z;
  const unsigned short* Bz = Bt + (long)zh*SBH;
  const float* biasz = bias + (long)zh*BIASST;
  int m0 = blockIdx.y*128, n0 = blockIdx.x*64;
  int tid = threadIdx.x;
  int lane = tid & 63, wid = tid >> 6;
  int wm = wid >> 1, wn = wid & 1;
  f32x4 zero4 = {0.f,0.f,0.f,0.f};
  f32x4 acc[4][2];
  #pragma unroll
  for (int m=0;m<4;m++)
    #pragma unroll
    for (int n=0;n<2;n++)
      acc[m][n] = zero4;
  const int r16 = lane & 15, kq = lane >> 4;

  const unsigned short* pA[4];
  const unsigned short* pB[2];
  #pragma unroll
  for (int i=0;i<4;i++){
    int chunk = i*256 + tid;                // 1024 chunks (128 rows x 8)
    int row = chunk >> 3, c = chunk & 7;
    int cg = (c ^ (row & 7)) * 8;
    pA[i] = A + (long)(m0 + row)*Kt + cg;
  }
  #pragma unroll
  for (int i=0;i<2;i++){
    int chunk = i*256 + tid;                // 512 chunks (64 rows x 8)
    int row = chunk >> 3, c = chunk & 7;
    int cg = (c ^ (row & 7)) * 8;
    pB[i] = Bz + (long)(n0 + row)*Kt + cg;
  }
  auto stage = [&](int buf, int k0){
    unsigned short* As = (unsigned short*)shraw[buf];
    #pragma unroll
    for (int i=0;i<4;i++) GLOAD(pA[i] + k0, As + (i*256 + wid*64)*8);
    #pragma unroll
    for (int i=0;i<2;i++) GLOAD(pB[i] + k0, As + 8192 + (i*256 + wid*64)*8);
  };

  constexpr int NT = Kt/64;
  stage(0, 0);
  asm volatile("s_waitcnt vmcnt(0)" ::: "memory");
  __builtin_amdgcn_s_barrier();
  for (int t = 0; t < NT; t++){
    if (t + 1 < NT) stage((t+1)&1, (t+1)*64);
    const unsigned short* As = (const unsigned short*)shraw[t&1];
    const unsigned short* Bs = As + 8192;
    #pragma unroll
    for (int kk=0; kk<64; kk+=32){
      short8 af[4], bfr[2];
      int kb = (kk + kq*8) * 2;
      #pragma unroll
      for (int m=0;m<4;m++){
        int row = wm*64 + m*16 + r16;
        af[m] = *(const short8*)((const char*)As + row*128 + (kb ^ ((row & 7) << 4)));
      }
      #pragma unroll
      for (int n=0;n<2;n++){
        int row = wn*32 + n*16 + r16;
        bfr[n] = *(const short8*)((const char*)Bs + row*128 + (kb ^ ((row & 7) << 4)));
      }
      __builtin_amdgcn_s_setprio(1);
      #pragma unroll
      for (int m=0;m<4;m++)
        #pragma unroll
        for (int n=0;n<2;n++)
          acc[m][n] = __builtin_amdgcn_mfma_f32_16x16x32_bf16(af[m], bfr[n], acc[m][n], 0, 0, 0);
      __builtin_amdgcn_s_setprio(0);
    }
    if (t + 1 < NT) asm volatile("s_waitcnt vmcnt(0)" ::: "memory");
    __builtin_amdgcn_s_barrier();
  }

  if (MODE == 1 || MODE == 2){
    // bf16 tile 128x64 via LDS (stride 72 shorts = 144B = 9*16B)
    unsigned short* shb = (unsigned short*)&shraw[0][0];
    #pragma unroll
    for (int n=0;n<2;n++){
      int col = wn*32 + n*16 + r16;
      float bvv = biasz[n0 + col];
      #pragma unroll
      for (int m=0;m<4;m++){
        #pragma unroll
        for (int e=0;e<4;e++){
          int row = wm*64 + m*16 + kq*4 + e;
          float vv = acc[m][n][e] + bvv;
          if (MODE == 2) vv = 0.5f*vv*(1.f + erff(vv*0.7071067811865475f));
          shb[row*72 + col] = f2bf(vv);
        }
      }
    }
    __syncthreads();
    // 128x64 = 1024 chunks of 8 shorts
    #pragma unroll
    for (int i=0;i<4;i++){
      int chunk = i*256 + tid;
      int row = chunk >> 3, col = (chunk & 7)*8;
      short8 vv8 = *(const short8*)(shb + row*72 + col);
      *(short8*)((unsigned short*)Cout + (long)zh*SCH +
                 (long)(m0 + row)*Nt + n0 + col) = vv8;
    }
  } else {
    // MODE 3: fp32 +=, two 64-row phases via LDS (stride 72 floats = 288B)
    float* shf = (float*)&shraw[0][0];
    #pragma unroll
    for (int ph=0; ph<2; ph++){
      __syncthreads();
      if (wm == ph){
        #pragma unroll
        for (int n=0;n<2;n++){
          int col = wn*32 + n*16 + r16;
          float bvv = biasz[n0 + col];
          #pragma unroll
          for (int m=0;m<4;m++){
            #pragma unroll
            for (int e=0;e<4;e++){
              int rl = m*16 + kq*4 + e;
              shf[rl*72 + col] = acc[m][n][e] + bvv;
            }
          }
        }
      }
      __syncthreads();
      // 64x64 floats = 1024 float4 chunks
      #pragma unroll
      for (int i=0;i<4;i++){
        int chunk = i*256 + tid;
        int row = chunk >> 4, col = (chunk & 15)*4;
        float4 vv = *(const float4*)(shf + row*72 + col);
        float* cp = (float*)Cout + (long)(m0 + ph*64 + row)*Nt + n0 + col;
        float4 o = *(const float4*)cp;
        o.x += vv.x; o.y += vv.y; o.z += vv.z; o.w += vv.w;
        *(float4*)cp = o;
      }
    }
  }
}

// ---------------------------------------------------------------------------
extern "C" void kernel_launch(void* const* d_in, const int* in_sizes, int n_in,
                              void* d_out, int out_size, void* d_ws, size_t ws_size,
                              hipStream_t stream){
  const int*   tokens = (const int*)  d_in[0];
  const float* embedp = (const float*)d_in[1];
  const float* pos    = (const float*)d_in[2];
  const float* Wq  = (const float*)d_in[3];
  const float* bq  = (const float*)d_in[4];
  const float* Wk  = (const float*)d_in[5];
  const float* bk  = (const float*)d_in[6];
  const float* Wv  = (const float*)d_in[7];
  const float* bv  = (const float*)d_in[8];
  const float* Wo  = (const float*)d_in[9];
  const float* bo  = (const float*)d_in[10];
  const float* ln1g= (const float*)d_in[11];
  const float* ln1b= (const float*)d_in[12];
  const float* ln2g= (const float*)d_in[13];
  const float* ln2b= (const float*)d_in[14];
  const float* W1  = (const float*)d_in[15];
  const float* b1  = (const float*)d_in[16];
  const float* W2  = (const float*)d_in[17];
  const float* b2  = (const float*)d_in[18];
  const float* gates=(const float*)d_in[19];
  const float* lnfg= (const float*)d_in[20];
  const float* lnfb= (const float*)d_in[21];
  float* out = (float*)d_out;

  char* base = (char*)d_ws;
  size_t off = 0;
  auto take = [&](size_t bytes)->char*{
    char* p = base + off;
    off = (off + bytes + 255) & ~(size_t)255;
    return p;
  };
  unsigned short* WqT = (unsigned short*)take((size_t)Ln*Dn*Dn*2);
  unsigned short* WkT = (unsigned short*)take((size_t)Ln*Dn*Dn*2);
  unsigned short* WvT = (unsigned short*)take((size_t)Ln*Dn*Dn*2);
  unsigned short* WoT = (unsigned short*)take((size_t)Ln*Dn*Dn*2);
  unsigned short* W1T = (unsigned short*)take((size_t)Ln*Dn*Fn*2);
  unsigned short* W2T = (unsigned short*)take((size_t)Ln*Dn*Fn*2);
  unsigned short* wkvT= (unsigned short*)take((size_t)Ln*4*512*1024*2);
  float*          bkv = (float*)take((size_t)Ln*4*512*4);
  unsigned short* G   = (unsigned short*)take((size_t)Ln*Hn*Tn*Tn*2);
  float*          cbuf= (float*)take((size_t)Ln*Hn*Tn*4);
  float*          x   = (float*)take((size_t)Bn*Tn*Dn*4);
  unsigned short* hbuf= (unsigned short*)take((size_t)Bn*Tn*Dn*2);
  unsigned short* q   = (unsigned short*)take((size_t)Bn*Tn*Dn*2);
  unsigned short* kvbuf=(unsigned short*)take((size_t)15360*512*2);
  unsigned short* P   = (unsigned short*)take((size_t)7168*1024*2);
  unsigned short* vTp = (unsigned short*)take((size_t)Bn*1920*HDn*2);
  unsigned short* oT  = (unsigned short*)take((size_t)Hn*Bn*HDn*Tn*2);
  unsigned short* ao  = (unsigned short*)take((size_t)Bn*Tn*Dn*2);
  unsigned short* ff1 = (unsigned short*)take((size_t)Bn*Tn*Fn*2);
  unsigned short* attnA = (unsigned short*)take((size_t)Bn*1920*Tn*2);
  if (off > ws_size) return;   // workspace insufficient: bail (output stays 0)
  float* scoresA = (float*)ff1;   // packed fp32 scores alias (ff1 dead then)

  // ---- one-time-per-launch precompute ----
  transpose_w<<<dim3(Dn/32, Dn/32, Ln), 256, 0, stream>>>(Wq, WqT, Dn, Dn);
  transpose_w<<<dim3(Dn/32, Dn/32, Ln), 256, 0, stream>>>(Wk, WkT, Dn, Dn);
  transpose_w<<<dim3(Dn/32, Dn/32, Ln), 256, 0, stream>>>(Wv, WvT, Dn, Dn);
  transpose_w<<<dim3(Dn/32, Dn/32, Ln), 256, 0, stream>>>(Wo, WoT, Dn, Dn);
  transpose_w<<<dim3(Fn/32, Dn/32, Ln), 256, 0, stream>>>(W1, W1T, Dn, Fn);
  transpose_w<<<dim3(Dn/32, Fn/32, Ln), 256, 0, stream>>>(W2, W2T, Fn, Dn);
  pack_wkv<<<(Ln*4*512*128)/256, 256, 0, stream>>>(WkT, WvT, wkvT);
  pack_bkv<<<(Ln*4*512)/256, 256, 0, stream>>>(bk, bv, bkv);
  ckern<<<Ln*Hn, 512, 0, stream>>>(gates, cbuf);
  gfill<<<(Ln*Hn*Tn*Tn)/256, 256, 0, stream>>>(cbuf, G);
  embed_kernel<<<Bn*Tn, 256, 0, stream>>>(tokens, embedp, pos, x);

  const int MT = Bn*Tn;   // 8192

  for (int l=0; l<Ln; l++){
    // LN1 -> hbuf (bf16)
    ln_kernel<1><<<MT, 256, 0, stream>>>(x, ln1g + l*Dn, ln1b + l*Dn, hbuf);
    // pooled inputs for groups 1..3
    pool_x<<<7168, 256, 0, stream>>>(hbuf, P);
    // Q + grouped pooled K/V projection in ONE launch (z = 0..5)
    gemm_qkv<<<dim3(4, 64, 6), 256, 0, stream>>>(
        hbuf, P, WqT + (size_t)l*Dn*Dn, wkvT + (size_t)l*4*512*1024,
        q, kvbuf, bq + l*Dn, bkv + (size_t)l*4*512);
    // V-part transpose into vTp (layout pv_all consumes)
    vtrans<<<dim3(16, 4, 128), 256, 0, stream>>>(kvbuf, vTp);

    // scores for ALL heads -> packed scoresA
    scores_all<<<dim3(4, Tn/128, 128), 256, 0, stream>>>(q, kvbuf, scoresA);
    // softmax for ALL heads (8 rows/block)
    softmax_all<<<(8*MT)/8, 512, 0, stream>>>(scoresA, attnA);
    // PV for ALL heads -> oT[zh][zb][d][t]
    pv_all<<<dim3(Tn/128, 1, 128), 256, 0, stream>>>(vTp, attnA, oT);

    // spectral gating, all 8 heads in ONE launch
    gemm_kernel<1><<<dim3(1, Tn/128, 128), 256, 0, stream>>>(
        G + (size_t)(l*Hn)*Tn*Tn, Tn, 0L, (long)Tn*Tn,
        oT, Tn, (long)HDn*Tn, (long)Bn*HDn*Tn,
        ao, Dn, (long)Tn*Dn, (long)HDn,
        nullptr, 0L, 4, 15,
        Tn, HDn, Tn);
    // Wo projection + residual into x (fp32): 128x64 tiles
    gemm_big<3, 8192, Dn, Dn, 0L, 0L, 0>
        <<<dim3(Dn/64, MT/128, 1), 256, 0, stream>>>(
        ao, WoT + (size_t)l*Dn*Dn, x, bo + l*Dn);
    // LN2 -> hbuf
    ln_kernel<1><<<MT, 256, 0, stream>>>(x, ln2g + l*Dn, ln2b + l*Dn, hbuf);
    // FFN1: GELU(h@W1+b1) -> ff1 (bf16)   [scoresA alias dead now]
    gemm_big<2, 8192, Fn, Dn, 0L, 0L, 0>
        <<<dim3(Fn/64, MT/128, 1), 256, 0, stream>>>(
        hbuf, W1T + (size_t)l*Dn*Fn, ff1, b1 + l*Fn);
    // FFN2 + residual into x
    gemm_big<3, 8192, Dn, Fn, 0L, 0L, 0>
        <<<dim3(Dn/64, MT/128, 1), 256, 0, stream>>>(
        ff1, W2T + (size_t)l*Dn*Fn, x, b2 + l*Dn);
  }
  // final LN -> d_out (fp32)
  ln_kernel<0><<<MT, 256, 0, stream>>>(x, lnfg, lnfb, out);
}

// Round 18
// 2748.138 us; speedup vs baseline: 1.0176x; 1.0176x over previous
//
#include <hip/hip_runtime.h>
#include <hip/hip_bf16.h>
#include <math.h>

#define Bn 16
#define Tn 512
#define Dn 1024
#define Hn 8
#define Ln 6
#define Fn 4096
#define HDn 128

typedef __attribute__((ext_vector_type(8))) short short8;
typedef __attribute__((ext_vector_type(4))) short short4v;
typedef __attribute__((ext_vector_type(4))) float f32x4;

__device__ __forceinline__ float bf2f(unsigned short u){
  union{float f; unsigned int i;} c; c.i = ((unsigned int)u)<<16; return c.f;
}
__device__ __forceinline__ unsigned short f2bf(float f){
  union{float f; unsigned int i;} c; c.f=f;
  unsigned int r = c.i + 0x7fffu + ((c.i>>16)&1u);
  return (unsigned short)(r>>16);
}
// pref(h): pooled-token prefix offset (rows of S) for head h; S_h = 512>>(h>>1)
__device__ __forceinline__ int pref_of(int h){
  int g = h >> 1;
  return (2048 - (2048 >> g)) + (h & 1) * (512 >> g);
}
__device__ __forceinline__ int kvoff_of(int g){   // row offset of group g in kvbuf
  return (g==0)?0:(g==1)?8192:(g==2)?12288:14336;
}

#define GLOAD(gp, lp) __builtin_amdgcn_global_load_lds( \
    (const __attribute__((address_space(1))) void*)(const void*)(gp), \
    (__attribute__((address_space(3))) void*)(void*)(lp), 16, 0, 0)

// ---------------- embedding: x[b,t,:] = embed[tok] + pos[t] ----------------
__global__ __launch_bounds__(256) void embed_kernel(
    const int* __restrict__ tok, const float* __restrict__ emb,
    const float* __restrict__ pos, float* __restrict__ x){
  long row = blockIdx.x;                 // b*T + t
  int t = (int)(row & (Tn-1));
  int tk = tok[row];
  int d = threadIdx.x*4;
  float4 e = *(const float4*)(emb + (long)tk*Dn + d);
  float4 p = *(const float4*)(pos + (long)t*Dn + d);
  float4 r; r.x=e.x+p.x; r.y=e.y+p.y; r.z=e.z+p.z; r.w=e.w+p.w;
  *(float4*)(x + row*(long)Dn + d) = r;
}

// ---------------- LayerNorm over D=1024 (one block per row) ----------------
template<int OUTBF>
__global__ __launch_bounds__(256) void ln_kernel(
    const float* __restrict__ x, const float* __restrict__ g,
    const float* __restrict__ b, void* __restrict__ outp){
  long row = blockIdx.x;
  const float* xr = x + row*(long)Dn;
  int tid = threadIdx.x;
  float4 v4 = *(const float4*)(xr + tid*4);
  float s  = v4.x+v4.y+v4.z+v4.w;
  float s2 = v4.x*v4.x + v4.y*v4.y + v4.z*v4.z + v4.w*v4.w;
  #pragma unroll
  for (int o=32;o;o>>=1){ s += __shfl_xor(s,o); s2 += __shfl_xor(s2,o); }
  __shared__ float rs[4], rs2[4];
  int w = tid>>6;
  if ((tid&63)==0){ rs[w]=s; rs2[w]=s2; }
  __syncthreads();
  s  = rs[0]+rs[1]+rs[2]+rs[3];
  s2 = rs2[0]+rs2[1]+rs2[2]+rs2[3];
  float mu  = s*(1.f/Dn);
  float var = s2*(1.f/Dn) - mu*mu;
  float rstd = rsqrtf(var + 1e-5f);
  float4 gg = *(const float4*)(g + tid*4);
  float4 bb = *(const float4*)(b + tid*4);
  float o0 = (v4.x-mu)*rstd*gg.x + bb.x;
  float o1 = (v4.y-mu)*rstd*gg.y + bb.y;
  float o2 = (v4.z-mu)*rstd*gg.z + bb.z;
  float o3 = (v4.w-mu)*rstd*gg.w + bb.w;
  if (OUTBF){
    unsigned short* o = (unsigned short*)outp + row*(long)Dn + tid*4;
    o[0]=f2bf(o0); o[1]=f2bf(o1); o[2]=f2bf(o2); o[3]=f2bf(o3);
  } else {
    float* o = (float*)outp + row*(long)Dn + tid*4;
    o[0]=o0; o[1]=o1; o[2]=o2; o[3]=o3;
  }
}

// ------------- weight transpose+convert: W[K][N] f32 -> WT[N][K] bf16 -------
__global__ __launch_bounds__(256) void transpose_w(
    const float* __restrict__ W, unsigned short* __restrict__ WT, int Kd, int Nd){
  __shared__ float tile[32][33];
  long lofs = (long)blockIdx.z * Kd * Nd;
  int n0 = blockIdx.x*32, k0 = blockIdx.y*32;
  int tx = threadIdx.x & 31, ty = threadIdx.x >> 5;   // ty 0..7
  #pragma unroll
  for (int i=0;i<4;i++){
    int kk = k0 + ty + i*8;
    tile[ty+i*8][tx] = W[lofs + (long)kk*Nd + n0 + tx];
  }
  __syncthreads();
  #pragma unroll
  for (int i=0;i<4;i++){
    int nn = n0 + ty + i*8;
    WT[lofs + (long)nn*Kd + k0 + tx] = f2bf(tile[tx][ty+i*8]);
  }
}

// ---- pack grouped K/V weights: wkvT[l][g][512][1024] from WkT, WvT --------
__global__ __launch_bounds__(256) void pack_wkv(
    const unsigned short* __restrict__ WkT, const unsigned short* __restrict__ WvT,
    unsigned short* __restrict__ wkvT){
  int i8 = blockIdx.x*256 + threadIdx.x;    // short8 chunk index
  int c8 = i8 & 127;
  int r  = (i8 >> 7) & 511;
  int g  = (i8 >> 16) & 3;
  int l  = i8 >> 18;
  const unsigned short* src = (r < 256)
      ? WkT + ((long)l<<20) + (long)(g*256 + r)*1024 + c8*8
      : WvT + ((long)l<<20) + (long)(g*256 + (r-256))*1024 + c8*8;
  *(short8*)(wkvT + (long)i8*8) = *(const short8*)src;
}

// ---- pack grouped K/V biases: bkv[l][g][512] --------------------------------
__global__ __launch_bounds__(256) void pack_bkv(
    const float* __restrict__ bk, const float* __restrict__ bv,
    float* __restrict__ bkv){
  int i = blockIdx.x*256 + threadIdx.x;     // < Ln*4*512
  int c = i & 511;
  int g = (i >> 9) & 3;
  int l = i >> 11;
  bkv[i] = (c < 256) ? bk[l*1024 + g*256 + c] : bv[l*1024 + g*256 + (c-256)];
}

// ------- circulant kernel c = irfft(gate per rfft-bin), per (layer,head) ----
__global__ __launch_bounds__(512) void ckern(
    const float* __restrict__ gates, float* __restrict__ cbuf){
  int lh = blockIdx.x;                   // l*H + h
  __shared__ float gb[16];
  if (threadIdx.x < 16) gb[threadIdx.x] = gates[lh*16 + threadIdx.x];
  __syncthreads();
  int m = threadIdx.x;                   // 0..511
  float acc = gb[0];                     // bin 0, weight 1, band 0
  for (int j=1;j<256;j++){
    int band = (j*16)/257;               // (j*BANDS)//nb
    int kmod = (j*m) & 511;              // exact phase reduction
    acc += 2.f*gb[band]*cosf(1.2271846303085129e-2f * (float)kmod); // 2pi/512
  }
  acc += gb[15] * ((m & 1) ? -1.f : 1.f);   // Nyquist bin, band 15
  cbuf[lh*512 + m] = acc * (1.f/512.f);
}

// --------- materialize G[l,h,t,s] = c[(t-s) mod 512] as bf16 ---------------
__global__ __launch_bounds__(256) void gfill(
    const float* __restrict__ cbuf, unsigned short* __restrict__ G){
  long idx = (long)blockIdx.x*256 + threadIdx.x;   // grid sized exactly
  int lh = (int)(idx >> 18);
  int rem = (int)(idx & 262143);
  int t = rem >> 9, s = rem & 511;
  G[idx] = f2bf(cbuf[lh*512 + ((t - s) & 511)]);
}

// ---- pool hbuf rows for groups g=1..3: P rows {4096,2048,1024} x 1024 -------
__global__ __launch_bounds__(256) void pool_x(
    const unsigned short* __restrict__ hbuf, unsigned short* __restrict__ P){
  int rid = blockIdx.x;                     // < 7168
  int g, S, idx;
  if (rid < 4096){ g=1; S=256; idx=rid; }
  else if (rid < 6144){ g=2; S=128; idx=rid-4096; }
  else { g=3; S=64; idx=rid-6144; }
  int r = 1 << g;
  int b = idx / S, s = idx - b*S;
  const unsigned short* src = hbuf + ((long)(b*512 + s*r))*1024 + threadIdx.x*4;
  float a0=0.f, a1=0.f, a2=0.f, a3=0.f;
  for (int j=0;j<r;j++){
    short4v v = *(const short4v*)(src + (long)j*1024);
    a0 += bf2f((unsigned short)v[0]); a1 += bf2f((unsigned short)v[1]);
    a2 += bf2f((unsigned short)v[2]); a3 += bf2f((unsigned short)v[3]);
  }
  float inv = 1.f/(float)r;
  unsigned short* dst = P + (long)rid*1024 + threadIdx.x*4;
  dst[0]=f2bf(a0*inv); dst[1]=f2bf(a1*inv); dst[2]=f2bf(a2*inv); dst[3]=f2bf(a3*inv);
}

// ---- transpose pooled V out of kvbuf into vTp[head-packed][b][d][s] ---------
__global__ __launch_bounds__(256) void vtrans(
    const unsigned short* __restrict__ kvbuf, unsigned short* __restrict__ vTp){
  __shared__ unsigned short tile[32][33];
  int z = blockIdx.z;                 // h*16 + b
  int h = z >> 4, b = z & 15;
  int g = h >> 1, dlt = h & 1;
  int S = 512 >> g;
  int s0 = blockIdx.x*32;
  if (s0 >= S) return;
  int d0 = blockIdx.y*32;
  int kvbase = kvoff_of(g) + b*S;
  int colbase = 256 + dlt*128 + d0;
  int tx = threadIdx.x & 31, ty = threadIdx.x >> 5;   // ty 0..7
  #pragma unroll
  for (int i=0;i<4;i++){
    int s = s0 + ty + i*8;
    tile[ty+i*8][tx] = kvbuf[(long)(kvbase + s)*512 + colbase + tx];
  }
  __syncthreads();
  long basep = (long)Bn*HDn*pref_of(h);
  #pragma unroll
  for (int i=0;i<4;i++){
    int d = d0 + ty + i*8;
    vTp[basep + ((long)(b*128 + d))*S + s0 + tx] = tile[tx][ty+i*8];
  }
}

// --------- merged row softmax over ALL heads (variable S per head) ----------
// 512 threads = 8 waves, one row per wave.
__global__ __launch_bounds__(512) void softmax_all(
    const float* __restrict__ sc, unsigned short* __restrict__ at){
  long rid = (long)blockIdx.x*8 + (threadIdx.x >> 6);
  int head = (int)(rid >> 13);
  int rih  = (int)(rid & 8191);
  int g = head >> 1;
  int S = 512 >> g;
  int NV = S >> 6;
  long base = (long)Bn*Tn*pref_of(head) + (long)rih*S;
  const float* r = sc + base;
  int lane = threadIdx.x & 63;
  float vals[8];
  float mx = -1e30f;
  #pragma unroll
  for (int i=0;i<8;i++){
    if (i < NV){ vals[i] = r[lane + i*64] * 0.08838834764831845f; mx = fmaxf(mx, vals[i]); }
  }
  #pragma unroll
  for (int o=32;o;o>>=1) mx = fmaxf(mx, __shfl_xor(mx, o));
  float sum = 0.f;
  #pragma unroll
  for (int i=0;i<8;i++){
    if (i < NV){ vals[i] = expf(vals[i]-mx); sum += vals[i]; }
  }
  #pragma unroll
  for (int o=32;o;o>>=1) sum += __shfl_xor(sum, o);
  float inv = 1.f/sum;
  unsigned short* ab = at + base;
  #pragma unroll
  for (int i=0;i<8;i++){
    if (i < NV) ab[lane + i*64] = f2bf(vals[i]*inv);
  }
}

// ----------------- generic batched bf16 MFMA GEMM (gating path) -------------
// r7-proven schedule: stage(t+1); vmcnt(8); barrier; compute; barrier.
template<int MODE>
__global__ __launch_bounds__(256)
void gemm_kernel(const unsigned short* __restrict__ A, int lda, long sAb, long sAh,
                 const unsigned short* __restrict__ Bt, int ldb, long sBb, long sBh,
                 void* __restrict__ Cout, int ldc, long sCb, long sCh,
                 const float* __restrict__ bias, long sbias,
                 int zshift, int zmask,
                 int M, int N, int K)
{
  __shared__ unsigned short AB[2][2][128*64];
  int z = blockIdx.z;
  int zb = z & zmask, zh = z >> zshift;
  const unsigned short* Az = A + (long)zb*sAb + (long)zh*sAh;
  const unsigned short* Bz = Bt + (long)zb*sBb + (long)zh*sBh;
  const float* biasz = bias ? (bias + (long)zh*sbias) : nullptr;
  int m0 = blockIdx.y*128, n0 = blockIdx.x*128;
  int tid = threadIdx.x;
  int lane = tid & 63, wid = tid >> 6;
  int wm = wid >> 1, wn = wid & 1;
  f32x4 zero4 = {0.f,0.f,0.f,0.f};
  f32x4 acc[4][4];
  #pragma unroll
  for (int m=0;m<4;m++)
    #pragma unroll
    for (int n=0;n<4;n++)
      acc[m][n] = zero4;
  const int r16 = lane & 15, kq = lane >> 4;

  auto stage = [&](int buf, int k0){
    #pragma unroll
    for (int i=0;i<4;i++){
      int chunk = i*256 + tid;
      int row = chunk >> 3, c = chunk & 7;
      int cg = (c ^ (row & 7)) * 8;
      int gm = m0 + row; gm = gm < M ? gm : M-1;
      GLOAD(Az + (long)gm*lda + k0 + cg, AB[buf][0] + (i*256 + wid*64)*8);
    }
    #pragma unroll
    for (int i=0;i<4;i++){
      int chunk = i*256 + tid;
      int row = chunk >> 3, c = chunk & 7;
      int cg = (c ^ (row & 7)) * 8;
      int gn = n0 + row; gn = gn < N ? gn : N-1;
      GLOAD(Bz + (long)gn*ldb + k0 + cg, AB[buf][1] + (i*256 + wid*64)*8);
    }
  };

  int NT = K >> 6;
  stage(0, 0);
  for (int t = 0; t < NT; t++){
    if (t + 1 < NT){
      stage((t+1)&1, (t+1)*64);
      asm volatile("s_waitcnt vmcnt(8)" ::: "memory");
    } else {
      asm volatile("s_waitcnt vmcnt(0)" ::: "memory");
    }
    __builtin_amdgcn_s_barrier();
    const unsigned short* As = AB[t&1][0];
    const unsigned short* Bs = AB[t&1][1];
    #pragma unroll
    for (int kk=0; kk<64; kk+=32){
      short8 af[4], bfr[4];
      int kb = (kk + kq*8) * 2;
      #pragma unroll
      for (int m=0;m<4;m++){
        int row = wm*64 + m*16 + r16;
        af[m] = *(const short8*)((const char*)As + row*128 + (kb ^ ((row & 7) << 4)));
      }
      #pragma unroll
      for (int n=0;n<4;n++){
        int row = wn*64 + n*16 + r16;
        bfr[n] = *(const short8*)((const char*)Bs + row*128 + (kb ^ ((row & 7) << 4)));
      }
      #pragma unroll
      for (int m=0;m<4;m++)
        #pragma unroll
        for (int n=0;n<4;n++)
          acc[m][n] = __builtin_amdgcn_mfma_f32_16x16x32_bf16(af[m], bfr[n], acc[m][n], 0, 0, 0);
    }
    __builtin_amdgcn_s_barrier();
  }
  #pragma unroll
  for (int n=0;n<4;n++){
    int col = n0 + wn*64 + n*16 + r16;
    if (col >= N) continue;
    float bvv = 0.f;
    if (MODE != 0 && biasz != nullptr) bvv = biasz[col];
    #pragma unroll
    for (int m=0;m<4;m++){
      #pragma unroll
      for (int e=0;e<4;e++){
        int row = m0 + wm*64 + m*16 + kq*4 + e;
        if (row >= M) continue;
        float vv = acc[m][n][e] + bvv;
        long cidx = (long)zb*sCb + (long)zh*sCh + (long)row*ldc + col;
        if (MODE == 0)      ((float*)Cout)[cidx] = vv;
        else                ((unsigned short*)Cout)[cidx] = f2bf(vv);
      }
    }
  }
}

// -------- merged scores GEMM, all heads: reads k-half of kvbuf (ldb=512) ----
__global__ __launch_bounds__(256)
void scores_all(const unsigned short* __restrict__ q,
                const unsigned short* __restrict__ kvbuf,
                float* __restrict__ sc)
{
  __shared__ unsigned short AB[2][2][128*64];
  int z = blockIdx.z;
  int zb = z & 15, zh = z >> 4;
  int g = zh >> 1, dlt = zh & 1;
  int S = 512 >> g;
  int n0 = blockIdx.x*128;
  if (n0 >= S) return;
  int pf = pref_of(zh);
  const unsigned short* Az = q + (long)zb*Tn*Dn + (long)zh*HDn;
  const unsigned short* Bz = kvbuf + (long)(kvoff_of(g) + zb*S)*512 + dlt*128;
  float* Cz = sc + (long)Bn*Tn*pf + (long)zb*Tn*S;
  int m0 = blockIdx.y*128;
  int tid = threadIdx.x;
  int lane = tid & 63, wid = tid >> 6;
  int wm = wid >> 1, wn = wid & 1;
  f32x4 zero4 = {0.f,0.f,0.f,0.f};
  f32x4 acc[4][4];
  #pragma unroll
  for (int m=0;m<4;m++)
    #pragma unroll
    for (int n=0;n<4;n++)
      acc[m][n] = zero4;
  const int r16 = lane & 15, kq = lane >> 4;

  auto stage = [&](int buf, int k0){
    #pragma unroll
    for (int i=0;i<4;i++){
      int chunk = i*256 + tid;
      int row = chunk >> 3, c = chunk & 7;
      int cg = (c ^ (row & 7)) * 8;
      GLOAD(Az + (long)(m0 + row)*Dn + k0 + cg, AB[buf][0] + (i*256 + wid*64)*8);
    }
    #pragma unroll
    for (int i=0;i<4;i++){
      int chunk = i*256 + tid;
      int row = chunk >> 3, c = chunk & 7;
      int cg = (c ^ (row & 7)) * 8;
      int gn = n0 + row; gn = gn < S ? gn : S-1;
      GLOAD(Bz + (long)gn*512 + k0 + cg, AB[buf][1] + (i*256 + wid*64)*8);
    }
  };

  stage(0, 0);
  stage(1, 64);                             // K = HDn = 128 -> exactly 2 tiles
  #pragma unroll
  for (int t = 0; t < 2; t++){
    if (t == 0) { asm volatile("s_waitcnt vmcnt(8)" ::: "memory"); }
    else        { asm volatile("s_waitcnt vmcnt(0)" ::: "memory"); }
    __builtin_amdgcn_s_barrier();
    const unsigned short* As = AB[t][0];
    const unsigned short* Bs = AB[t][1];
    #pragma unroll
    for (int kk=0; kk<64; kk+=32){
      short8 af[4], bfr[4];
      int kb = (kk + kq*8) * 2;
      #pragma unroll
      for (int m=0;m<4;m++){
        int row = wm*64 + m*16 + r16;
        af[m] = *(const short8*)((const char*)As + row*128 + (kb ^ ((row & 7) << 4)));
      }
      #pragma unroll
      for (int n=0;n<4;n++){
        int row = wn*64 + n*16 + r16;
        bfr[n] = *(const short8*)((const char*)Bs + row*128 + (kb ^ ((row & 7) << 4)));
      }
      #pragma unroll
      for (int m=0;m<4;m++)
        #pragma unroll
        for (int n=0;n<4;n++)
          acc[m][n] = __builtin_amdgcn_mfma_f32_16x16x32_bf16(af[m], bfr[n], acc[m][n], 0, 0, 0);
    }
    __builtin_amdgcn_s_barrier();
  }
  #pragma unroll
  for (int n=0;n<4;n++){
    int col = n0 + wn*64 + n*16 + r16;
    if (col >= S) continue;
    #pragma unroll
    for (int m=0;m<4;m++){
      #pragma unroll
      for (int e=0;e<4;e++){
        int row = m0 + wm*64 + m*16 + kq*4 + e;
        Cz[(long)row*S + col] = acc[m][n][e];
      }
    }
  }
}

// -------- merged PV GEMM, all heads: oT[zh][zb][d][t], runtime K=S(zh) ------
__global__ __launch_bounds__(256)
void pv_all(const unsigned short* __restrict__ vTp,
            const unsigned short* __restrict__ at,
            unsigned short* __restrict__ oT)
{
  __shared__ unsigned short AB[2][2][128*64];
  int z = blockIdx.z;
  int zb = z & 15, zh = z >> 4;
  int g = zh >> 1;
  int S = 512 >> g;
  int pf = pref_of(zh);
  const unsigned short* Az = vTp + (long)Bn*HDn*pf + (long)zb*HDn*S;
  const unsigned short* Bz = at  + (long)Bn*Tn*pf  + (long)zb*Tn*S;
  unsigned short* Cz = oT + (long)zh*Bn*HDn*Tn + (long)zb*HDn*Tn;
  int n0 = blockIdx.x*128;
  int tid = threadIdx.x;
  int lane = tid & 63, wid = tid >> 6;
  int wm = wid >> 1, wn = wid & 1;
  f32x4 zero4 = {0.f,0.f,0.f,0.f};
  f32x4 acc[4][4];
  #pragma unroll
  for (int m=0;m<4;m++)
    #pragma unroll
    for (int n=0;n<4;n++)
      acc[m][n] = zero4;
  const int r16 = lane & 15, kq = lane >> 4;

  auto stage = [&](int buf, int k0){
    #pragma unroll
    for (int i=0;i<4;i++){
      int chunk = i*256 + tid;
      int row = chunk >> 3, c = chunk & 7;
      int cg = (c ^ (row & 7)) * 8;
      GLOAD(Az + (long)row*S + k0 + cg, AB[buf][0] + (i*256 + wid*64)*8);
    }
    #pragma unroll
    for (int i=0;i<4;i++){
      int chunk = i*256 + tid;
      int row = chunk >> 3, c = chunk & 7;
      int cg = (c ^ (row & 7)) * 8;
      GLOAD(Bz + (long)(n0 + row)*S + k0 + cg, AB[buf][1] + (i*256 + wid*64)*8);
    }
  };

  int NT = S >> 6;
  stage(0, 0);
  for (int t = 0; t < NT; t++){
    if (t + 1 < NT){
      stage((t+1)&1, (t+1)*64);
      asm volatile("s_waitcnt vmcnt(8)" ::: "memory");
    } else {
      asm volatile("s_waitcnt vmcnt(0)" ::: "memory");
    }
    __builtin_amdgcn_s_barrier();
    const unsigned short* As = AB[t&1][0];
    const unsigned short* Bs = AB[t&1][1];
    #pragma unroll
    for (int kk=0; kk<64; kk+=32){
      short8 af[4], bfr[4];
      int kb = (kk + kq*8) * 2;
      #pragma unroll
      for (int m=0;m<4;m++){
        int row = wm*64 + m*16 + r16;
        af[m] = *(const short8*)((const char*)As + row*128 + (kb ^ ((row & 7) << 4)));
      }
      #pragma unroll
      for (int n=0;n<4;n++){
        int row = wn*64 + n*16 + r16;
        bfr[n] = *(const short8*)((const char*)Bs + row*128 + (kb ^ ((row & 7) << 4)));
      }
      #pragma unroll
      for (int m=0;m<4;m++)
        #pragma unroll
        for (int n=0;n<4;n++)
          acc[m][n] = __builtin_amdgcn_mfma_f32_16x16x32_bf16(af[m], bfr[n], acc[m][n], 0, 0, 0);
    }
    __builtin_amdgcn_s_barrier();
  }
  #pragma unroll
  for (int n=0;n<4;n++){
    int col = n0 + wn*64 + n*16 + r16;
    #pragma unroll
    for (int m=0;m<4;m++){
      #pragma unroll
      for (int e=0;e<4;e++){
        int row = wm*64 + m*16 + kq*4 + e;
        Cz[(long)row*Tn + col] = f2bf(acc[m][n][e]);
      }
    }
  }
}

// ---- merged Q + grouped-K/V projection (z: 0,1 = Q halves; 2..5 = groups) --
// r7 2-barrier schedule; all sub-problems N=512 wide, K=1024.
__global__ __launch_bounds__(256)
void gemm_qkv(const unsigned short* __restrict__ hbuf,
              const unsigned short* __restrict__ P,
              const unsigned short* __restrict__ WqT_l,
              const unsigned short* __restrict__ wkvT_l,
              unsigned short* __restrict__ q,
              unsigned short* __restrict__ kvbuf,
              const float* __restrict__ bq_l,
              const float* __restrict__ bkv_l)
{
  __shared__ char shraw[2][32768];
  int z = blockIdx.z;
  int isQ = (z < 2);
  int g = isQ ? 0 : (z - 2);
  int Mg = isQ ? 8192 : (8192 >> g);
  int m0 = blockIdx.y*128;
  if (m0 >= Mg) return;                     // uniform exit, before any barrier
  int n0 = blockIdx.x*128;
  const unsigned short* Az = (isQ || g==0) ? hbuf
      : P + (long)((g==1)?0:(g==2)?4096:6144)*1024;
  const unsigned short* Bz = isQ ? (WqT_l + (long)z*512*1024)
                                 : (wkvT_l + (long)g*512*1024);
  const float* biasz = isQ ? (bq_l + z*512) : (bkv_l + g*512);
  unsigned short* Cz; int ldc;
  if (isQ){ Cz = q + z*512; ldc = 1024; }
  else    { Cz = kvbuf + (long)kvoff_of(g)*512; ldc = 512; }
  int tid = threadIdx.x;
  int lane = tid & 63, wid = tid >> 6;
  int wm = wid >> 1, wn = wid & 1;
  f32x4 zero4 = {0.f,0.f,0.f,0.f};
  f32x4 acc[4][4];
  #pragma unroll
  for (int m=0;m<4;m++)
    #pragma unroll
    for (int n=0;n<4;n++)
      acc[m][n] = zero4;
  const int r16 = lane & 15, kq = lane >> 4;

  auto stage = [&](int buf, int k0){
    unsigned short* As = (unsigned short*)shraw[buf];
    #pragma unroll
    for (int i=0;i<4;i++){
      int chunk = i*256 + tid;
      int row = chunk >> 3, c = chunk & 7;
      int cg = (c ^ (row & 7)) * 8;
      GLOAD(Az + (long)(m0 + row)*1024 + k0 + cg, As + (i*256 + wid*64)*8);
    }
    #pragma unroll
    for (int i=0;i<4;i++){
      int chunk = i*256 + tid;
      int row = chunk >> 3, c = chunk & 7;
      int cg = (c ^ (row & 7)) * 8;
      GLOAD(Bz + (long)(n0 + row)*1024 + k0 + cg, As + 8192 + (i*256 + wid*64)*8);
    }
  };

  const int NT = 16;                        // K = 1024
  stage(0, 0);
  for (int t = 0; t < NT; t++){
    if (t + 1 < NT){
      stage((t+1)&1, (t+1)*64);
      asm volatile("s_waitcnt vmcnt(8)" ::: "memory");
    } else {
      asm volatile("s_waitcnt vmcnt(0)" ::: "memory");
    }
    __builtin_amdgcn_s_barrier();
    const unsigned short* As = (const unsigned short*)shraw[t&1];
    const unsigned short* Bs = As + 8192;
    #pragma unroll
    for (int kk=0; kk<64; kk+=32){
      short8 af[4], bfr[4];
      int kb = (kk + kq*8) * 2;
      #pragma unroll
      for (int m=0;m<4;m++){
        int row = wm*64 + m*16 + r16;
        af[m] = *(const short8*)((const char*)As + row*128 + (kb ^ ((row & 7) << 4)));
      }
      #pragma unroll
      for (int n=0;n<4;n++){
        int row = wn*64 + n*16 + r16;
        bfr[n] = *(const short8*)((const char*)Bs + row*128 + (kb ^ ((row & 7) << 4)));
      }
      #pragma unroll
      for (int m=0;m<4;m++)
        #pragma unroll
        for (int n=0;n<4;n++)
          acc[m][n] = __builtin_amdgcn_mfma_f32_16x16x32_bf16(af[m], bfr[n], acc[m][n], 0, 0, 0);
    }
    __builtin_amdgcn_s_barrier();
  }

  unsigned short* shb = (unsigned short*)&shraw[0][0];
  #pragma unroll
  for (int n=0;n<4;n++){
    int col = wn*64 + n*16 + r16;
    float bvv = biasz[n0 + col];
    #pragma unroll
    for (int m=0;m<4;m++){
      #pragma unroll
      for (int e=0;e<4;e++){
        int row = wm*64 + m*16 + kq*4 + e;
        shb[row*136 + col] = f2bf(acc[m][n][e] + bvv);
      }
    }
  }
  __syncthreads();
  #pragma unroll
  for (int i=0;i<8;i++){
    int chunk = i*256 + tid;
    int row = chunk >> 4, col = (chunk & 15)*8;
    short8 vv8 = *(const short8*)(shb + row*136 + col);
    *(short8*)(Cz + (long)(m0 + row)*ldc + n0 + col) = vv8;
  }
}

// ----------------- static-shape 128-tile GEMM (dense projections) -----------
// r9-proven SINGLE-barrier schedule (+setprio).
// MODE 1: +bias -> bf16 | 2: +bias,GELU -> bf16 | 3: +bias, += into fp32 C
template<int MODE, int Mt, int Nt, int Kt, long SBH, long SCH, int BIASST>
__global__ __launch_bounds__(256)
void gemm_big(const unsigned short* __restrict__ A,
              const unsigned short* __restrict__ Bt,
              void* __restrict__ Cout,
              const float* __restrict__ bias)
{
  __shared__ char shraw[2][32768];
  int zh = blockIdx.z;
  const unsigned short* Bz = Bt + (long)zh*SBH;
  const float* biasz = bias + (long)zh*BIASST;
  int m0 = blockIdx.y*128, n0 = blockIdx.x*128;
  int tid = threadIdx.x;
  int lane = tid & 63, wid = tid >> 6;
  int wm = wid >> 1, wn = wid & 1;
  f32x4 zero4 = {0.f,0.f,0.f,0.f};
  f32x4 acc[4][4];
  #pragma unroll
  for (int m=0;m<4;m++)
    #pragma unroll
    for (int n=0;n<4;n++)
      acc[m][n] = zero4;
  const int r16 = lane & 15, kq = lane >> 4;

  const unsigned short* pA[4];
  const unsigned short* pB[4];
  #pragma unroll
  for (int i=0;i<4;i++){
    int chunk = i*256 + tid;
    int row = chunk >> 3, c = chunk & 7;
    int cg = (c ^ (row & 7)) * 8;
    pA[i] = A  + (long)(m0 + row)*Kt + cg;
    pB[i] = Bz + (long)(n0 + row)*Kt + cg;
  }
  auto stage = [&](int buf, int k0){
    unsigned short* As = (unsigned short*)shraw[buf];
    #pragma unroll
    for (int i=0;i<4;i++) GLOAD(pA[i] + k0, As + (i*256 + wid*64)*8);
    #pragma unroll
    for (int i=0;i<4;i++) GLOAD(pB[i] + k0, As + 8192 + (i*256 + wid*64)*8);
  };

  constexpr int NT = Kt/64;
  stage(0, 0);
  asm volatile("s_waitcnt vmcnt(0)" ::: "memory");
  __builtin_amdgcn_s_barrier();
  for (int t = 0; t < NT; t++){
    if (t + 1 < NT) stage((t+1)&1, (t+1)*64);
    const unsigned short* As = (const unsigned short*)shraw[t&1];
    const unsigned short* Bs = As + 8192;
    #pragma unroll
    for (int kk=0; kk<64; kk+=32){
      short8 af[4], bfr[4];
      int kb = (kk + kq*8) * 2;
      #pragma unroll
      for (int m=0;m<4;m++){
        int row = wm*64 + m*16 + r16;
        af[m] = *(const short8*)((const char*)As + row*128 + (kb ^ ((row & 7) << 4)));
      }
      #pragma unroll
      for (int n=0;n<4;n++){
        int row = wn*64 + n*16 + r16;
        bfr[n] = *(const short8*)((const char*)Bs + row*128 + (kb ^ ((row & 7) << 4)));
      }
      __builtin_amdgcn_s_setprio(1);
      #pragma unroll
      for (int m=0;m<4;m++)
        #pragma unroll
        for (int n=0;n<4;n++)
          acc[m][n] = __builtin_amdgcn_mfma_f32_16x16x32_bf16(af[m], bfr[n], acc[m][n], 0, 0, 0);
      __builtin_amdgcn_s_setprio(0);
    }
    if (t + 1 < NT) asm volatile("s_waitcnt vmcnt(0)" ::: "memory");
    __builtin_amdgcn_s_barrier();
  }

  if (MODE == 1 || MODE == 2){
    unsigned short* shb = (unsigned short*)&shraw[0][0];
    #pragma unroll
    for (int n=0;n<4;n++){
      int col = wn*64 + n*16 + r16;
      float bvv = biasz[n0 + col];
      #pragma unroll
      for (int m=0;m<4;m++){
        #pragma unroll
        for (int e=0;e<4;e++){
          int row = wm*64 + m*16 + kq*4 + e;
          float vv = acc[m][n][e] + bvv;
          if (MODE == 2) vv = 0.5f*vv*(1.f + erff(vv*0.7071067811865475f));
          shb[row*136 + col] = f2bf(vv);
        }
      }
    }
    __syncthreads();
    #pragma unroll
    for (int i=0;i<8;i++){
      int chunk = i*256 + tid;
      int row = chunk >> 4, col = (chunk & 15)*8;
      short8 vv8 = *(const short8*)(shb + row*136 + col);
      *(short8*)((unsigned short*)Cout + (long)zh*SCH +
                 (long)(m0 + row)*Nt + n0 + col) = vv8;
    }
  } else {
    float* shf = (float*)&shraw[0][0];
    #pragma unroll
    for (int ph=0; ph<2; ph++){
      __syncthreads();
      if (wm == ph){
        #pragma unroll
        for (int n=0;n<4;n++){
          int col = wn*64 + n*16 + r16;
          float bvv = biasz[n0 + col];
          #pragma unroll
          for (int m=0;m<4;m++){
            #pragma unroll
            for (int e=0;e<4;e++){
              int rl = m*16 + kq*4 + e;
              shf[rl*136 + col] = acc[m][n][e] + bvv;
            }
          }
        }
      }
      __syncthreads();
      #pragma unroll
      for (int i=0;i<8;i++){
        int chunk = i*256 + tid;
        int row = chunk >> 5, col = (chunk & 31)*4;
        float4 vv = *(const float4*)(shf + row*136 + col);
        float* cp = (float*)Cout + (long)(m0 + ph*64 + row)*Nt + n0 + col;
        float4 o = *(const float4*)cp;
        o.x += vv.x; o.y += vv.y; o.z += vv.z; o.w += vv.w;
        *(float4*)cp = o;
      }
    }
  }
}

// ---------------------------------------------------------------------------
extern "C" void kernel_launch(void* const* d_in, const int* in_sizes, int n_in,
                              void* d_out, int out_size, void* d_ws, size_t ws_size,
                              hipStream_t stream){
  const int*   tokens = (const int*)  d_in[0];
  const float* embedp = (const float*)d_in[1];
  const float* pos    = (const float*)d_in[2];
  const float* Wq  = (const float*)d_in[3];
  const float* bq  = (const float*)d_in[4];
  const float* Wk  = (const float*)d_in[5];
  const float* bk  = (const float*)d_in[6];
  const float* Wv  = (const float*)d_in[7];
  const float* bv  = (const float*)d_in[8];
  const float* Wo  = (const float*)d_in[9];
  const float* bo  = (const float*)d_in[10];
  const float* ln1g= (const float*)d_in[11];
  const float* ln1b= (const float*)d_in[12];
  const float* ln2g= (const float*)d_in[13];
  const float* ln2b= (const float*)d_in[14];
  const float* W1  = (const float*)d_in[15];
  const float* b1  = (const float*)d_in[16];
  const float* W2  = (const float*)d_in[17];
  const float* b2  = (const float*)d_in[18];
  const float* gates=(const float*)d_in[19];
  const float* lnfg= (const float*)d_in[20];
  const float* lnfb= (const float*)d_in[21];
  float* out = (float*)d_out;

  char* base = (char*)d_ws;
  size_t off = 0;
  auto take = [&](size_t bytes)->char*{
    char* p = base + off;
    off = (off + bytes + 255) & ~(size_t)255;
    return p;
  };
  unsigned short* WqT = (unsigned short*)take((size_t)Ln*Dn*Dn*2);
  unsigned short* WkT = (unsigned short*)take((size_t)Ln*Dn*Dn*2);
  unsigned short* WvT = (unsigned short*)take((size_t)Ln*Dn*Dn*2);
  unsigned short* WoT = (unsigned short*)take((size_t)Ln*Dn*Dn*2);
  unsigned short* W1T = (unsigned short*)take((size_t)Ln*Dn*Fn*2);
  unsigned short* W2T = (unsigned short*)take((size_t)Ln*Dn*Fn*2);
  unsigned short* wkvT= (unsigned short*)take((size_t)Ln*4*512*1024*2);
  float*          bkv = (float*)take((size_t)Ln*4*512*4);
  unsigned short* G   = (unsigned short*)take((size_t)Ln*Hn*Tn*Tn*2);
  float*          cbuf= (float*)take((size_t)Ln*Hn*Tn*4);
  float*          x   = (float*)take((size_t)Bn*Tn*Dn*4);
  unsigned short* hbuf= (unsigned short*)take((size_t)Bn*Tn*Dn*2);
  unsigned short* q   = (unsigned short*)take((size_t)Bn*Tn*Dn*2);
  unsigned short* kvbuf=(unsigned short*)take((size_t)15360*512*2);
  unsigned short* P   = (unsigned short*)take((size_t)7168*1024*2);
  unsigned short* vTp = (unsigned short*)take((size_t)Bn*1920*HDn*2);
  unsigned short* oT  = (unsigned short*)take((size_t)Hn*Bn*HDn*Tn*2);
  unsigned short* ao  = (unsigned short*)take((size_t)Bn*Tn*Dn*2);
  unsigned short* ff1 = (unsigned short*)take((size_t)Bn*Tn*Fn*2);
  unsigned short* attnA = (unsigned short*)take((size_t)Bn*1920*Tn*2);
  if (off > ws_size) return;   // workspace insufficient: bail (output stays 0)
  float* scoresA = (float*)ff1;   // packed fp32 scores alias (ff1 dead then)

  // ---- one-time-per-launch precompute ----
  transpose_w<<<dim3(Dn/32, Dn/32, Ln), 256, 0, stream>>>(Wq, WqT, Dn, Dn);
  transpose_w<<<dim3(Dn/32, Dn/32, Ln), 256, 0, stream>>>(Wk, WkT, Dn, Dn);
  transpose_w<<<dim3(Dn/32, Dn/32, Ln), 256, 0, stream>>>(Wv, WvT, Dn, Dn);
  transpose_w<<<dim3(Dn/32, Dn/32, Ln), 256, 0, stream>>>(Wo, WoT, Dn, Dn);
  transpose_w<<<dim3(Fn/32, Dn/32, Ln), 256, 0, stream>>>(W1, W1T, Dn, Fn);
  transpose_w<<<dim3(Dn/32, Fn/32, Ln), 256, 0, stream>>>(W2, W2T, Fn, Dn);
  pack_wkv<<<(Ln*4*512*128)/256, 256, 0, stream>>>(WkT, WvT, wkvT);
  pack_bkv<<<(Ln*4*512)/256, 256, 0, stream>>>(bk, bv, bkv);
  ckern<<<Ln*Hn, 512, 0, stream>>>(gates, cbuf);
  gfill<<<(Ln*Hn*Tn*Tn)/256, 256, 0, stream>>>(cbuf, G);
  embed_kernel<<<Bn*Tn, 256, 0, stream>>>(tokens, embedp, pos, x);

  const int MT = Bn*Tn;   // 8192

  for (int l=0; l<Ln; l++){
    // LN1 -> hbuf (bf16)
    ln_kernel<1><<<MT, 256, 0, stream>>>(x, ln1g + l*Dn, ln1b + l*Dn, hbuf);
    // pooled inputs for groups 1..3
    pool_x<<<7168, 256, 0, stream>>>(hbuf, P);
    // Q + grouped pooled K/V projection in ONE launch (z = 0..5)
    gemm_qkv<<<dim3(4, 64, 6), 256, 0, stream>>>(
        hbuf, P, WqT + (size_t)l*Dn*Dn, wkvT + (size_t)l*4*512*1024,
        q, kvbuf, bq + l*Dn, bkv + (size_t)l*4*512);
    // V-part transpose into vTp (layout pv_all consumes)
    vtrans<<<dim3(16, 4, 128), 256, 0, stream>>>(kvbuf, vTp);

    // scores for ALL heads -> packed scoresA
    scores_all<<<dim3(4, Tn/128, 128), 256, 0, stream>>>(q, kvbuf, scoresA);
    // softmax for ALL heads (8 rows/block)
    softmax_all<<<(8*MT)/8, 512, 0, stream>>>(scoresA, attnA);
    // PV for ALL heads -> oT[zh][zb][d][t]
    pv_all<<<dim3(Tn/128, 1, 128), 256, 0, stream>>>(vTp, attnA, oT);

    // spectral gating, all 8 heads in ONE launch
    gemm_kernel<1><<<dim3(1, Tn/128, 128), 256, 0, stream>>>(
        G + (size_t)(l*Hn)*Tn*Tn, Tn, 0L, (long)Tn*Tn,
        oT, Tn, (long)HDn*Tn, (long)Bn*HDn*Tn,
        ao, Dn, (long)Tn*Dn, (long)HDn,
        nullptr, 0L, 4, 15,
        Tn, HDn, Tn);
    // Wo projection + residual into x (fp32)
    gemm_big<3, 8192, Dn, Dn, 0L, 0L, 0>
        <<<dim3(Dn/128, MT/128, 1), 256, 0, stream>>>(
        ao, WoT + (size_t)l*Dn*Dn, x, bo + l*Dn);
    // LN2 -> hbuf
    ln_kernel<1><<<MT, 256, 0, stream>>>(x, ln2g + l*Dn, ln2b + l*Dn, hbuf);
    // FFN1: GELU(h@W1+b1) -> ff1 (bf16)   [scoresA alias dead now]
    gemm_big<2, 8192, Fn, Dn, 0L, 0L, 0>
        <<<dim3(Fn/128, MT/128, 1), 256, 0, stream>>>(
        hbuf, W1T + (size_t)l*Dn*Fn, ff1, b1 + l*Fn);
    // FFN2 + residual into x
    gemm_big<3, 8192, Dn, Fn, 0L, 0L, 0>
        <<<dim3(Dn/128, MT/128, 1), 256, 0, stream>>>(
        ff1, W2T + (size_t)l*Dn*Fn, x, b2 + l*Dn);
  }
  // final LN -> d_out (fp32)
  ln_kernel<0><<<MT, 256, 0, stream>>>(x, lnfg, lnfb, out);
}